// Round 1
// baseline (37.017 us; speedup 1.0000x reference)
//
#include <hip/hip_runtime.h>

// SmoothnessLoss: mean over [B,4,H,W] of smooth_l1(stencil(in - tgt)) * mask
// B=16, C=1, H=W=1024, fp32 in/out. Output is a single fp32 scalar.
//
// Stencils on d = in - tgt (all 180-deg symmetric, so corr==conv):
//   fx  = d(y,x-1) - 2 d(y,x) + d(y,x+1)        mask: zero at x==W-1
//   fy  = d(y-1,x) - 2 d(y,x) + d(y+1,x)        mask: zero at y==H-1
//   fd1 = d(y-1,x-1) - 2 d(y,x) + d(y+1,x+1)    mask: zero on all borders
//   fd2 = d(y-1,x+1) - 2 d(y,x) + d(y+1,x-1)    mask: zero on all borders
// Zero padding outside the image.

#define BB 16
#define HH 1024
#define WW 1024
#define RR 8   // rows per block-strip; traffic = (RR+2)/RR x ideal

__device__ __forceinline__ float sl1(float v) {
  // smooth_l1, branchless: ad<1 -> 0.5 ad^2 ; else ad-0.5
  float ad = fabsf(v);
  float t = fminf(ad, 1.0f);
  return fmaf(0.5f * t, t, ad - t);
}

__global__ __launch_bounds__(256) void smooth_partial(
    const float* __restrict__ in, const float* __restrict__ tg,
    float* __restrict__ ws) {
  const int tid = threadIdx.x;
  const int x0  = tid * 4;                  // 256 threads x 4 cols = 1024 = W
  const int strip = blockIdx.x;             // 0 .. B*(H/RR)-1
  const int bi = strip / (HH / RR);
  const int r0 = (strip % (HH / RR)) * RR;
  const int imgBase = bi * (HH * WW);

  float pl, pr, cl, cr, nl, nr;
  float4 pc, cc, nc;

  auto loadRow = [&](int y, float4& c, float& l, float& r) {
    if (y < 0 || y >= HH) {
      c = make_float4(0.f, 0.f, 0.f, 0.f); l = 0.f; r = 0.f; return;
    }
    const int base = imgBase + y * WW;
    float4 a = *reinterpret_cast<const float4*>(in + base + x0);
    float4 b = *reinterpret_cast<const float4*>(tg + base + x0);
    c.x = a.x - b.x; c.y = a.y - b.y; c.z = a.z - b.z; c.w = a.w - b.w;
    l = (x0 > 0)       ? in[base + x0 - 1] - tg[base + x0 - 1] : 0.f;
    r = (x0 + 4 < WW)  ? in[base + x0 + 4] - tg[base + x0 + 4] : 0.f;
  };

  loadRow(r0 - 1, pc, pl, pr);
  loadRow(r0,     cc, cl, cr);

  float sum = 0.f;
  for (int k = 0; k < RR; ++k) {
    const int y = r0 + k;
    loadRow(y + 1, nc, nl, nr);

    const float P[6] = {pl, pc.x, pc.y, pc.z, pc.w, pr};
    const float C[6] = {cl, cc.x, cc.y, cc.z, cc.w, cr};
    const float N[6] = {nl, nc.x, nc.y, nc.z, nc.w, nr};

    const float my  = (y == HH - 1) ? 0.f : 1.f;
    const float mdy = (y == 0 || y == HH - 1) ? 0.f : 1.f;

    #pragma unroll
    for (int j = 1; j <= 4; ++j) {
      const int x = x0 + j - 1;
      const float c2 = -2.f * C[j];
      const float fx = (C[j-1] + C[j+1]) + c2;
      const float fy = (P[j]   + N[j]  ) + c2;
      const float f1 = (P[j-1] + N[j+1]) + c2;
      const float f2 = (P[j+1] + N[j-1]) + c2;
      const float mx  = (x == WW - 1) ? 0.f : 1.f;
      const float mdx = (x == 0 || x == WW - 1) ? 0.f : 1.f;
      sum += sl1(fx) * mx + sl1(fy) * my + (sl1(f1) + sl1(f2)) * (mdx * mdy);
    }

    pl = cl; pr = cr; pc = cc;
    cl = nl; cr = nr; cc = nc;
  }

  // deterministic block reduction: wave shuffle + LDS
  for (int off = 32; off > 0; off >>= 1) sum += __shfl_down(sum, off, 64);
  __shared__ float sh[4];
  const int wave = tid >> 6, lane = tid & 63;
  if (lane == 0) sh[wave] = sum;
  __syncthreads();
  if (tid == 0) ws[blockIdx.x] = (sh[0] + sh[1]) + (sh[2] + sh[3]);
}

__global__ __launch_bounds__(256) void smooth_final(
    const float* __restrict__ ws, float* __restrict__ out, int n) {
  float s = 0.f;
  for (int i = threadIdx.x; i < n; i += 256) s += ws[i];
  for (int off = 32; off > 0; off >>= 1) s += __shfl_down(s, off, 64);
  __shared__ float sh[4];
  const int wave = threadIdx.x >> 6, lane = threadIdx.x & 63;
  if (lane == 0) sh[wave] = s;
  __syncthreads();
  if (threadIdx.x == 0) {
    const float scale = 1.0f / (float)((long long)BB * 4LL * HH * WW);
    out[0] = ((sh[0] + sh[1]) + (sh[2] + sh[3])) * scale;
  }
}

extern "C" void kernel_launch(void* const* d_in, const int* in_sizes, int n_in,
                              void* d_out, int out_size, void* d_ws, size_t ws_size,
                              hipStream_t stream) {
  const float* in = (const float*)d_in[0];
  const float* tg = (const float*)d_in[1];
  float* out = (float*)d_out;
  float* ws  = (float*)d_ws;   // needs B*(H/RR)*4 = 8 KiB, well under ws_size

  const int nblocks = BB * (HH / RR);  // 2048 blocks, 256 threads each
  smooth_partial<<<nblocks, 256, 0, stream>>>(in, tg, ws);
  smooth_final<<<1, 256, 0, stream>>>(ws, out, nblocks);
}